// Round 7
// baseline (428.410 us; speedup 1.0000x reference)
//
#include <hip/hip_runtime.h>
#include <math.h>

// TransformerBlock for MI355X — round 7: barrier-free attention (K/V direct
// from L2, P-only LDS, 1-wave blocks), coalesced V-transpose epilogue in the
// qkv GEMM, LN1 merged into weight-prep. Numerics identical to round 6.
// ws: wT bf16 | R1 h/att/h2 hi,lo | R2 q->x2 f32 | R3 kh,vth,vtl -> gh,gl

#define TOKENS 8192
#define SEQ    2048
typedef unsigned short u16;
typedef __attribute__((ext_vector_type(8))) short bf16x8;
typedef __attribute__((ext_vector_type(4))) float f32x4;
typedef __attribute__((ext_vector_type(4))) unsigned short u16x4;

#define BAR_V0 asm volatile("s_waitcnt vmcnt(0) lgkmcnt(0)\n\ts_barrier" ::: "memory")

__device__ __forceinline__ u16 f2bf(float f) {
    unsigned u = __builtin_bit_cast(unsigned, f);
    u += 0x7fffu + ((u >> 16) & 1u);
    return (u16)(u >> 16);
}
__device__ __forceinline__ float bf2f(u16 h) {
    unsigned u = ((unsigned)h) << 16;
    return __builtin_bit_cast(float, u);
}
__device__ __forceinline__ void a16(void* lds, const void* g) {
    __builtin_amdgcn_global_load_lds(
        (const __attribute__((address_space(1))) unsigned int*)g,
        (__attribute__((address_space(3))) unsigned int*)lds, 16, 0, 0);
}
__device__ __forceinline__ float gelu_exact(float v) {
    return 0.5f * v * (1.0f + erff(v * 0.70710678118654752f));
}

// ---------------------------------------------------------------------------
// prep: blocks 0..511 = weight transpose->bf16; blocks 512..2559 = LN1.
// ---------------------------------------------------------------------------
__global__ __launch_bounds__(256) void prep_k(const float* __restrict__ wqkv,
                                              const float* __restrict__ wout,
                                              const float* __restrict__ w1,
                                              const float* __restrict__ w2,
                                              u16* __restrict__ dqkv,
                                              u16* __restrict__ dout,
                                              u16* __restrict__ d1,
                                              u16* __restrict__ d2,
                                              const float* __restrict__ x,
                                              const float* __restrict__ g,
                                              const float* __restrict__ bta,
                                              u16* __restrict__ oh,
                                              u16* __restrict__ ol) {
    const int tid = threadIdx.x;
    if (blockIdx.x >= 512) {
        // ---- LN1: 4 rows per block, one wave per 512-f32 row ----
        const int lane = tid & 63;
        const int row  = ((blockIdx.x - 512) << 2) + (tid >> 6);
        const float* xr = x + ((size_t)row << 9) + (lane << 3);
        float v[8];
        *(float4*)&v[0] = *(const float4*)xr;
        *(float4*)&v[4] = *(const float4*)(xr + 4);
        float s = 0.f, ss = 0.f;
#pragma unroll
        for (int i = 0; i < 8; i++) { s += v[i]; ss += v[i] * v[i]; }
#pragma unroll
        for (int m = 32; m; m >>= 1) {
            s  += __shfl_xor(s, m, 64);
            ss += __shfl_xor(ss, m, 64);
        }
        const float mu   = s * (1.0f / 512.0f);
        const float rstd = rsqrtf(ss * (1.0f / 512.0f) - mu * mu + 1e-5f);
        float gg[8], bb[8];
        *(float4*)&gg[0] = *(const float4*)(g + (lane << 3));
        *(float4*)&gg[4] = *(const float4*)(g + (lane << 3) + 4);
        *(float4*)&bb[0] = *(const float4*)(bta + (lane << 3));
        *(float4*)&bb[4] = *(const float4*)(bta + (lane << 3) + 4);
        union { u16 us[8]; uint4 q; } H, L;
#pragma unroll
        for (int i = 0; i < 8; i++) {
            float r = (v[i] - mu) * rstd * gg[i] + bb[i];
            u16 hi = f2bf(r);
            H.us[i] = hi;
            L.us[i] = f2bf(r - bf2f(hi));
        }
        const size_t o = ((size_t)row << 9) + (lane << 3);
        *(uint4*)&oh[o] = H.q;
        *(uint4*)&ol[o] = L.q;
        return;
    }
    // ---- weight transpose ----
    __shared__ float t[64][65];
    int b = blockIdx.x;
    const float* src; u16* dst; int K, N, n0, k0;
    if (b < 192)      { src = wqkv; dst = dqkv; K = 512;  N = 1536; n0 = (b % 24) << 6; k0 = (b / 24) << 6; }
    else if (b < 256) { b -= 192; src = wout; dst = dout; K = 512;  N = 512;  n0 = (b & 7) << 6;  k0 = (b >> 3) << 6; }
    else if (b < 384) { b -= 256; src = w1;   dst = d1;   K = 512;  N = 1024; n0 = (b & 15) << 6; k0 = (b >> 4) << 6; }
    else              { b -= 384; src = w2;   dst = d2;   K = 1024; N = 512;  n0 = (b & 7) << 6;  k0 = (b >> 3) << 6; }
    {
        const int kr = tid >> 2, nc = (tid & 3) << 4;
        const float* p = src + (size_t)(k0 + kr) * N + n0 + nc;
#pragma unroll
        for (int i = 0; i < 4; i++)
            *(float4*)&t[kr][nc + (i << 2)] = *(const float4*)(p + (i << 2));
    }
    __syncthreads();
    {
        const int nr = tid >> 2, kc = (tid & 3) << 4;
        union { u16 us[16]; uint4 q[2]; } H;
#pragma unroll
        for (int i = 0; i < 16; i++) H.us[i] = f2bf(t[kc + i][nr]);
        const size_t o = (size_t)(n0 + nr) * K + k0 + kc;
        *(uint4*)&dst[o] = H.q[0];
        *(uint4*)&dst[o + 8] = H.q[1];
    }
}

// ---------------------------------------------------------------------------
// LayerNorm (LN2) -> split bf16 hi/lo.
// ---------------------------------------------------------------------------
__global__ __launch_bounds__(256) void ln_k(const float* __restrict__ x,
                                            const float* __restrict__ g,
                                            const float* __restrict__ bta,
                                            u16* __restrict__ oh,
                                            u16* __restrict__ ol) {
    const int lane = threadIdx.x & 63;
    const int row  = (blockIdx.x << 2) + (threadIdx.x >> 6);
    const float* xr = x + ((size_t)row << 9) + (lane << 3);
    float v[8];
    *(float4*)&v[0] = *(const float4*)xr;
    *(float4*)&v[4] = *(const float4*)(xr + 4);
    float s = 0.f, ss = 0.f;
#pragma unroll
    for (int i = 0; i < 8; i++) { s += v[i]; ss += v[i] * v[i]; }
#pragma unroll
    for (int m = 32; m; m >>= 1) {
        s  += __shfl_xor(s, m, 64);
        ss += __shfl_xor(ss, m, 64);
    }
    const float mu   = s * (1.0f / 512.0f);
    const float rstd = rsqrtf(ss * (1.0f / 512.0f) - mu * mu + 1e-5f);
    float gg[8], bb[8];
    *(float4*)&gg[0] = *(const float4*)(g + (lane << 3));
    *(float4*)&gg[4] = *(const float4*)(g + (lane << 3) + 4);
    *(float4*)&bb[0] = *(const float4*)(bta + (lane << 3));
    *(float4*)&bb[4] = *(const float4*)(bta + (lane << 3) + 4);
    union { u16 us[8]; uint4 q; } H, L;
#pragma unroll
    for (int i = 0; i < 8; i++) {
        float r = (v[i] - mu) * rstd * gg[i] + bb[i];
        u16 hi = f2bf(r);
        H.us[i] = hi;
        L.us[i] = f2bf(r - bf2f(hi));
    }
    const size_t o = ((size_t)row << 9) + (lane << 3);
    *(uint4*)&oh[o] = H.q;
    *(uint4*)&ol[o] = L.q;
}

// ---------------------------------------------------------------------------
// 2-term split MFMA GEMM, double-buffered staging, asm barriers.
// EPI 0: qkv scatter; V region goes through an LDS transpose so vth/vtl are
// written as coalesced 16B chunks instead of 33M scattered 2B stores.
// ---------------------------------------------------------------------------
template <int EPI>
__global__ __launch_bounds__(256, 2) void sgemm_k(
    const u16* __restrict__ Ah, const u16* __restrict__ Al,
    const u16* __restrict__ Bh,
    const float* __restrict__ bias, const float* __restrict__ res,
    float* __restrict__ Cf, u16* __restrict__ Ch, u16* __restrict__ Cl,
    u16* __restrict__ Dh, u16* __restrict__ Dl,
    int M, int N, int K) {
    __shared__ u16 sm[24576];  // two 12288-u16 staging buffers; reused by V-epi
    const int tid = threadIdx.x;
    const int lane = tid & 63, wv = tid >> 6;
    const int col = lane & 15, quad = lane >> 4;
    const int wm = (wv & 1) << 6, wn = (wv >> 1) << 6;
    const int bm = blockIdx.y << 7, bn = blockIdx.x << 7;

    const int r0 = tid >> 2,         c0 = (tid & 3) ^ ((r0 >> 1) & 3);
    const int r1 = (tid + 256) >> 2, c1 = (tid & 3) ^ ((r1 >> 1) & 3);
    const u16* Ag0  = Ah + (size_t)(bm + r0) * K + c0 * 8;
    const u16* Ag1  = Ah + (size_t)(bm + r1) * K + c1 * 8;
    const u16* ALg0 = Al + (size_t)(bm + r0) * K + c0 * 8;
    const u16* ALg1 = Al + (size_t)(bm + r1) * K + c1 * 8;
    const u16* Bg0  = Bh + (size_t)(bn + r0) * K + c0 * 8;
    const u16* Bg1  = Bh + (size_t)(bn + r1) * K + c1 * 8;
    const int lw0 = wv * 512, lw1 = wv * 512 + 2048;
    const int swz = (col >> 1) & 3;
    const f32x4 z4 = {0.f, 0.f, 0.f, 0.f};
    f32x4 acc[4][4] = {{z4,z4,z4,z4},{z4,z4,z4,z4},{z4,z4,z4,z4},{z4,z4,z4,z4}};

    a16(&sm[lw0],        Ag0);  a16(&sm[lw1],        Ag1);
    a16(&sm[lw0 + 4096], ALg0); a16(&sm[lw1 + 4096], ALg1);
    a16(&sm[lw0 + 8192], Bg0);  a16(&sm[lw1 + 8192], Bg1);

    int ib = 0;
    for (int k0 = 0; k0 < K; k0 += 32, ib ^= 1) {
        BAR_V0;
        if (k0 + 32 < K) {
            const int nb = (ib ^ 1) * 12288;
            const int kn = k0 + 32;
            a16(&sm[nb + lw0],        Ag0 + kn);  a16(&sm[nb + lw1],        Ag1 + kn);
            a16(&sm[nb + lw0 + 4096], ALg0 + kn); a16(&sm[nb + lw1 + 4096], ALg1 + kn);
            a16(&sm[nb + lw0 + 8192], Bg0 + kn);  a16(&sm[nb + lw1 + 8192], Bg1 + kn);
        }
        const int cb = ib * 12288;
        bf16x8 af[4][2];
#pragma unroll
        for (int mt = 0; mt < 4; mt++) {
            const int ra = cb + (wm + (mt << 4) + col) * 32 + ((quad ^ swz) << 3);
            af[mt][0] = *(const bf16x8*)&sm[ra];
            af[mt][1] = *(const bf16x8*)&sm[4096 + ra];
        }
#pragma unroll
        for (int nt = 0; nt < 4; nt++) {
            const int rb = cb + 8192 + (wn + (nt << 4) + col) * 32 + ((quad ^ swz) << 3);
            bf16x8 bh_ = *(const bf16x8*)&sm[rb];
#pragma unroll
            for (int mt = 0; mt < 4; mt++) {
                acc[mt][nt] = __builtin_amdgcn_mfma_f32_16x16x32_bf16(af[mt][0], bh_, acc[mt][nt], 0, 0, 0);
                acc[mt][nt] = __builtin_amdgcn_mfma_f32_16x16x32_bf16(af[mt][1], bh_, acc[mt][nt], 0, 0, 0);
            }
        }
    }

    if constexpr (EPI == 0) {
        if (bn >= 1024) {
            // ---- V region: LDS transpose -> coalesced vth/vtl stores ----
            const int hd0  = (bn - 1024) >> 6;
            const int b8   = (bm >> 11) << 3;
            const int keyb = bm & 2047;
            u16* smH = sm;
            u16* smL = sm + 8704;      // 64 rows x 136
            __syncthreads();           // all waves done with staging buffers
#pragma unroll
            for (int hf = 0; hf < 2; hf++) {
                if ((wv >> 1) == hf) {
#pragma unroll
                    for (int mt = 0; mt < 4; mt++)
#pragma unroll
                    for (int rr = 0; rr < 4; rr++) {
                        const int key = wm + (mt << 4) + (quad << 2) + rr;
#pragma unroll
                        for (int nt = 0; nt < 4; nt++) {
                            const int dl = (nt << 4) + col;
                            float v = acc[mt][nt][rr];
                            u16 hi = f2bf(v);
                            smH[dl * 136 + key] = hi;
                            smL[dl * 136 + key] = f2bf(v - bf2f(hi));
                        }
                    }
                }
                __syncthreads();
                {
                    const int d = tid >> 2;
#pragma unroll
                    for (int c = 0; c < 4; c++) {
                        const int key0 = ((((tid & 3) << 2) + c) << 3);
                        const size_t gb = ((size_t)(b8 + hd0 + hf) << 17)
                                        + ((size_t)d << 11) + keyb + key0;
                        *(uint4*)&Dh[gb] = *(const uint4*)&smH[d * 136 + key0];
                        *(uint4*)&Dl[gb] = *(const uint4*)&smL[d * 136 + key0];
                    }
                }
                __syncthreads();
            }
            return;
        }
    }

    float bs[4];
    if constexpr (EPI >= 1) {
#pragma unroll
        for (int nt = 0; nt < 4; nt++) bs[nt] = bias[bn + wn + (nt << 4) + col];
    }
#pragma unroll
    for (int mt = 0; mt < 4; mt++) {
#pragma unroll
        for (int rr = 0; rr < 4; rr++) {
            const int row = bm + wm + (mt << 4) + (quad << 2) + rr;
#pragma unroll
            for (int nt = 0; nt < 4; nt++) {
                const int colg = bn + wn + (nt << 4) + col;
                float v = acc[mt][nt][rr];
                if constexpr (EPI == 0) {
                    const int b = row >> 11, key = row & 2047;
                    if (bn < 512) {
                        Cf[((size_t)row << 9) + colg] = v;
                    } else {
                        const int hd = (colg - 512) >> 6, d = colg & 63;
                        Ch[((size_t)((b << 3) + hd) << 17) + (key << 6) + d] = f2bf(v);
                    }
                } else if constexpr (EPI == 2) {
                    v = gelu_exact(v + bs[nt]);
                    const size_t o = (size_t)row * N + colg;
                    u16 hi = f2bf(v);
                    Ch[o] = hi; Cl[o] = f2bf(v - bf2f(hi));
                } else {
                    const size_t o = (size_t)row * N + colg;
                    Cf[o] = v + bs[nt] + res[o];
                }
            }
        }
    }
}

// ---------------------------------------------------------------------------
// Flash attention, barrier-free: 1 wave per block, 32 q-rows (2 subtiles).
// K/V fragments read directly from global (L2-resident); only P round-trips
// LDS (wave-private, 4KB, no barriers anywhere). Grid (64 qt, 32 bh).
// K single bf16 [bh][key][d]; V split bf16 vt [bh][d][key]; Q split f32->bf16.
// ---------------------------------------------------------------------------
__global__ __launch_bounds__(64, 3) void attn_k(const float* __restrict__ q,
                                                const u16* __restrict__ kh,
                                                const u16* __restrict__ vth,
                                                const u16* __restrict__ vtl,
                                                u16* __restrict__ ah,
                                                u16* __restrict__ al) {
    __shared__ u16 sm[2048];   // P tile: 32 rows x 64 keys
    const int lane = threadIdx.x & 63;
    const int col = lane & 15, quad = lane >> 4;
    const int qt = blockIdx.x, bh = blockIdx.y;
    const int b = bh >> 3, h = bh & 7;
    const size_t tok0 = (size_t)b * SEQ;
    const size_t bhK = (size_t)bh << 17;
    const int q0 = qt << 5;

    // Q fragments for both subtiles (B-operand; 0.125 folded in)
    bf16x8 qfh[2][2], qfl[2][2];
#pragma unroll
    for (int sub = 0; sub < 2; sub++) {
        const int qrow = q0 + (sub << 4) + col;
        const float* qp = q + ((tok0 + qrow) << 9) + (h << 6) + (quad << 3);
#pragma unroll
        for (int kc = 0; kc < 2; kc++) {
            float v[8];
            *(float4*)&v[0] = *(const float4*)(qp + (kc << 5));
            *(float4*)&v[4] = *(const float4*)(qp + (kc << 5) + 4);
            union { u16 us[8]; bf16x8 v8; } H, L;
#pragma unroll
            for (int i = 0; i < 8; i++) {
                float f = v[i] * 0.125f;
                u16 hi = f2bf(f);
                H.us[i] = hi;
                L.us[i] = f2bf(f - bf2f(hi));
            }
            qfh[sub][kc] = H.v8; qfl[sub][kc] = L.v8;
        }
    }

    const f32x4 z4 = {0.f, 0.f, 0.f, 0.f};
    f32x4 o[2][4] = {{z4, z4, z4, z4}, {z4, z4, z4, z4}};
    float m_run[2] = {-1e30f, -1e30f}, l_run[2] = {0.f, 0.f};

    // per-lane global fragment bases
    const u16* kbase = kh + bhK + ((size_t)col << 6) + (quad << 3);   // + jt*4096 + kb*1024 + kc*32
    const size_t vb  = bhK + ((size_t)col << 11) + (quad << 3);       // + db*32768 + jt*64 + kc*32
    const u16* vhb = vth + vb;
    const u16* vlb = vtl + vb;

    for (int jt = 0; jt < 32; jt++) {
        // ---- St[key][q] = K · Qᵀ, K A-frags straight from L2 ----
        const u16* kjt = kbase + ((size_t)jt << 12);
        f32x4 st0[4] = {z4, z4, z4, z4}, st1[4] = {z4, z4, z4, z4};
#pragma unroll
        for (int kb = 0; kb < 4; kb++) {
#pragma unroll
            for (int kc = 0; kc < 2; kc++) {
                bf16x8 khf = *(const bf16x8*)(kjt + (kb << 10) + (kc << 5));
                st0[kb] = __builtin_amdgcn_mfma_f32_16x16x32_bf16(khf, qfh[0][kc], st0[kb], 0, 0, 0);
                st0[kb] = __builtin_amdgcn_mfma_f32_16x16x32_bf16(khf, qfl[0][kc], st0[kb], 0, 0, 0);
                st1[kb] = __builtin_amdgcn_mfma_f32_16x16x32_bf16(khf, qfh[1][kc], st1[kb], 0, 0, 0);
                st1[kb] = __builtin_amdgcn_mfma_f32_16x16x32_bf16(khf, qfl[1][kc], st1[kb], 0, 0, 0);
            }
        }

        // ---- online softmax + P->LDS per subtile (wave-private) ----
#pragma unroll
        for (int sub = 0; sub < 2; sub++) {
            f32x4* st = sub ? st1 : st0;
            float mx = st[0][0];
#pragma unroll
            for (int kb = 0; kb < 4; kb++)
#pragma unroll
                for (int r = 0; r < 4; r++) mx = fmaxf(mx, st[kb][r]);
            mx = fmaxf(mx, __shfl_xor(mx, 16));
            mx = fmaxf(mx, __shfl_xor(mx, 32));
            const float mn = fmaxf(m_run[sub], mx);
            const float alp = __expf(m_run[sub] - mn);
            m_run[sub] = mn;
            float p[16];
            float rs = 0.0f;
#pragma unroll
            for (int kb = 0; kb < 4; kb++)
#pragma unroll
                for (int r = 0; r < 4; r++) {
                    float e = __expf(st[kb][r] - mn);
                    p[(kb << 2) + r] = e;
                    rs += e;
                }
            rs += __shfl_xor(rs, 16);
            rs += __shfl_xor(rs, 32);
            l_run[sub] = l_run[sub] * alp + rs;
            float aO[4];
#pragma unroll
            for (int r = 0; r < 4; r++) aO[r] = __shfl(alp, (quad << 2) + r);
#pragma unroll
            for (int db = 0; db < 4; db++) {
                o[sub][db][0] *= aO[0]; o[sub][db][1] *= aO[1];
                o[sub][db][2] *= aO[2]; o[sub][db][3] *= aO[3];
            }
            const int prow = (sub << 4) + col;
            const int p64 = prow << 6, p7 = prow & 7;
#pragma unroll
            for (int kb = 0; kb < 4; kb++) {
                u16x4 hv;
#pragma unroll
                for (int r = 0; r < 4; r++) hv[r] = f2bf(p[(kb << 2) + r]);
                const int c = (kb << 1) + (quad >> 1);
                *(u16x4*)&sm[p64 + ((c ^ p7) << 3) + ((quad & 1) << 2)] = hv;
            }
        }

        // ---- P A-frags back (same-wave DS ordering, no barrier) ----
        bf16x8 pf[2][2];
#pragma unroll
        for (int sub = 0; sub < 2; sub++) {
            const int prow = (sub << 4) + col;
            const int p64 = prow << 6, p7 = prow & 7;
#pragma unroll
            for (int kc = 0; kc < 2; kc++)
                pf[sub][kc] = *(const bf16x8*)&sm[p64 + ((((kc << 2) + quad) ^ p7) << 3)];
        }

        // ---- O += P · V, V B-frags straight from L2 ----
        const size_t vjt = (size_t)jt << 6;
#pragma unroll
        for (int db = 0; db < 4; db++) {
            const size_t dof = vjt + ((size_t)db << 15);
#pragma unroll
            for (int kc = 0; kc < 2; kc++) {
                bf16x8 vh = *(const bf16x8*)(vhb + dof + (kc << 5));
                bf16x8 vl = *(const bf16x8*)(vlb + dof + (kc << 5));
                o[0][db] = __builtin_amdgcn_mfma_f32_16x16x32_bf16(pf[0][kc], vh, o[0][db], 0, 0, 0);
                o[0][db] = __builtin_amdgcn_mfma_f32_16x16x32_bf16(pf[0][kc], vl, o[0][db], 0, 0, 0);
                o[1][db] = __builtin_amdgcn_mfma_f32_16x16x32_bf16(pf[1][kc], vh, o[1][db], 0, 0, 0);
                o[1][db] = __builtin_amdgcn_mfma_f32_16x16x32_bf16(pf[1][kc], vl, o[1][db], 0, 0, 0);
            }
        }
    }

    // ---- epilogue: O/l -> split bf16 attended [tok][h*64+d] ----
#pragma unroll
    for (int sub = 0; sub < 2; sub++) {
        float linv[4];
#pragma unroll
        for (int r = 0; r < 4; r++) linv[r] = 1.0f / __shfl(l_run[sub], (quad << 2) + r);
#pragma unroll
        for (int r = 0; r < 4; r++) {
            const size_t rowo = ((tok0 + q0 + (sub << 4) + (quad << 2) + r) << 9)
                                + (h << 6) + col;
#pragma unroll
            for (int db = 0; db < 4; db++) {
                float v = o[sub][db][r] * linv[r];
                u16 hi = f2bf(v);
                ah[rowo + (db << 4)] = hi;
                al[rowo + (db << 4)] = f2bf(v - bf2f(hi));
            }
        }
    }
}

// ---------------------------------------------------------------------------
extern "C" void kernel_launch(void* const* d_in, const int* in_sizes, int n_in,
                              void* d_out, int out_size, void* d_ws, size_t ws_size,
                              hipStream_t stream) {
    const float* x     = (const float*)d_in[0];
    const float* ln1_g = (const float*)d_in[1];
    const float* ln1_b = (const float*)d_in[2];
    const float* w_qkv = (const float*)d_in[3];
    const float* w_out = (const float*)d_in[4];
    const float* b_out = (const float*)d_in[5];
    const float* ln2_g = (const float*)d_in[6];
    const float* ln2_b = (const float*)d_in[7];
    const float* w1    = (const float*)d_in[8];
    const float* b1    = (const float*)d_in[9];
    const float* w2    = (const float*)d_in[10];
    const float* b2    = (const float*)d_in[11];
    float* out = (float*)d_out;

    u16* wqkvh = (u16*)d_ws;                       // [1536][512]
    u16* wouth = wqkvh + 1536 * 512;               // [512][512]
    u16* w1h   = wouth + 512 * 512;                // [1024][512]
    u16* w2h   = w1h + 1024 * 512;                 // [512][1024]
    u16* R1    = w2h + 512 * 1024;
    u16* hh = R1, *hl = R1 + (size_t)TOKENS * 512;
    float* R2  = (float*)(R1 + (size_t)2 * TOKENS * 512);  // q -> x2
    float* qbuf = R2, *x2 = R2;
    u16* R3  = (u16*)(R2 + (size_t)TOKENS * 512);
    u16* kh  = R3;                                 // [32][2048][64]
    u16* vth = kh + (size_t)32 * 131072;           // [32][64][2048]
    u16* vtl = vth + (size_t)32 * 131072;
    u16* gh  = R3, *gl = R3 + (size_t)TOKENS * 1024;  // gelu out (aliases k/v)

    prep_k<<<2560, 256, 0, stream>>>(w_qkv, w_out, w1, w2, wqkvh, wouth, w1h, w2h,
                                     x, ln1_g, ln1_b, hh, hl);
    sgemm_k<0><<<dim3(12, 64), 256, 0, stream>>>(hh, hl, wqkvh, nullptr, nullptr,
                                                 qbuf, kh, nullptr, vth, vtl,
                                                 TOKENS, 1536, 512);
    attn_k<<<dim3(64, 32), 64, 0, stream>>>(qbuf, kh, vth, vtl, hh, hl);
    sgemm_k<1><<<dim3(4, 64), 256, 0, stream>>>(hh, hl, wouth, b_out, x,
                                                x2, nullptr, nullptr, nullptr, nullptr,
                                                TOKENS, 512, 512);
    ln_k<<<TOKENS / 4, 256, 0, stream>>>(x2, ln2_g, ln2_b, hh, hl);
    sgemm_k<2><<<dim3(8, 64), 256, 0, stream>>>(hh, hl, w1h, b1, nullptr,
                                                nullptr, gh, gl, nullptr, nullptr,
                                                TOKENS, 1024, 512);
    sgemm_k<3><<<dim3(4, 64), 256, 0, stream>>>(gh, gl, w2h, b2, x2,
                                                out, nullptr, nullptr, nullptr, nullptr,
                                                TOKENS, 512, 1024);
}

// Round 8
// 255.558 us; speedup vs baseline: 1.6764x; 1.6764x over previous
//
#include <hip/hip_runtime.h>
#include <math.h>

// TransformerBlock for MI355X — round 8: single-rounded fp16 operands
// everywhere (err 2^-11, better than prior bf16-split schemes), fp32
// accumulate. Halves MFMA count, LDS traffic, and staging vs round 6.
// attn: R6 structure (K dbuf, V latency-hidden, asm barriers).
// ws: wT fp16 | hbuf fp16 (h/att/gelu-in) | qbuf f32 -> x2 f32 | kh,vth fp16 -> gh

#define TOKENS 8192
#define SEQ    2048
typedef unsigned short u16;
typedef __attribute__((ext_vector_type(8))) _Float16 h8;
typedef __attribute__((ext_vector_type(4))) float f32x4;
typedef __attribute__((ext_vector_type(4))) unsigned short u16x4;

#define BAR_V0 asm volatile("s_waitcnt vmcnt(0) lgkmcnt(0)\n\ts_barrier" ::: "memory")
#define BAR_V4 asm volatile("s_waitcnt vmcnt(4) lgkmcnt(0)\n\ts_barrier" ::: "memory")

__device__ __forceinline__ u16 f2h(float f) {
    _Float16 h = (_Float16)f;               // v_cvt_f16_f32, RTNE
    return __builtin_bit_cast(u16, h);
}
__device__ __forceinline__ void a16(void* lds, const void* g) {
    __builtin_amdgcn_global_load_lds(
        (const __attribute__((address_space(1))) unsigned int*)g,
        (__attribute__((address_space(3))) unsigned int*)lds, 16, 0, 0);
}
__device__ __forceinline__ float gelu_exact(float v) {
    return 0.5f * v * (1.0f + erff(v * 0.70710678118654752f));
}

// ---------------------------------------------------------------------------
// prep: blocks 0..511 = weight transpose -> fp16 [N][K]; 512..2559 = LN1 -> fp16.
// ---------------------------------------------------------------------------
__global__ __launch_bounds__(256) void prep_k(const float* __restrict__ wqkv,
                                              const float* __restrict__ wout,
                                              const float* __restrict__ w1,
                                              const float* __restrict__ w2,
                                              u16* __restrict__ dqkv,
                                              u16* __restrict__ dout,
                                              u16* __restrict__ d1,
                                              u16* __restrict__ d2,
                                              const float* __restrict__ x,
                                              const float* __restrict__ g,
                                              const float* __restrict__ bta,
                                              u16* __restrict__ oh) {
    const int tid = threadIdx.x;
    if (blockIdx.x >= 512) {
        const int lane = tid & 63;
        const int row  = ((blockIdx.x - 512) << 2) + (tid >> 6);
        const float* xr = x + ((size_t)row << 9) + (lane << 3);
        float v[8];
        *(float4*)&v[0] = *(const float4*)xr;
        *(float4*)&v[4] = *(const float4*)(xr + 4);
        float s = 0.f, ss = 0.f;
#pragma unroll
        for (int i = 0; i < 8; i++) { s += v[i]; ss += v[i] * v[i]; }
#pragma unroll
        for (int m = 32; m; m >>= 1) {
            s  += __shfl_xor(s, m, 64);
            ss += __shfl_xor(ss, m, 64);
        }
        const float mu   = s * (1.0f / 512.0f);
        const float rstd = rsqrtf(ss * (1.0f / 512.0f) - mu * mu + 1e-5f);
        float gg[8], bb[8];
        *(float4*)&gg[0] = *(const float4*)(g + (lane << 3));
        *(float4*)&gg[4] = *(const float4*)(g + (lane << 3) + 4);
        *(float4*)&bb[0] = *(const float4*)(bta + (lane << 3));
        *(float4*)&bb[4] = *(const float4*)(bta + (lane << 3) + 4);
        union { u16 us[8]; uint4 q; } H;
#pragma unroll
        for (int i = 0; i < 8; i++) H.us[i] = f2h((v[i] - mu) * rstd * gg[i] + bb[i]);
        *(uint4*)&oh[((size_t)row << 9) + (lane << 3)] = H.q;
        return;
    }
    __shared__ float t[64][65];
    int b = blockIdx.x;
    const float* src; u16* dst; int K, N, n0, k0;
    if (b < 192)      { src = wqkv; dst = dqkv; K = 512;  N = 1536; n0 = (b % 24) << 6; k0 = (b / 24) << 6; }
    else if (b < 256) { b -= 192; src = wout; dst = dout; K = 512;  N = 512;  n0 = (b & 7) << 6;  k0 = (b >> 3) << 6; }
    else if (b < 384) { b -= 256; src = w1;   dst = d1;   K = 512;  N = 1024; n0 = (b & 15) << 6; k0 = (b >> 4) << 6; }
    else              { b -= 384; src = w2;   dst = d2;   K = 1024; N = 512;  n0 = (b & 7) << 6;  k0 = (b >> 3) << 6; }
    {
        const int kr = tid >> 2, nc = (tid & 3) << 4;
        const float* p = src + (size_t)(k0 + kr) * N + n0 + nc;
#pragma unroll
        for (int i = 0; i < 4; i++)
            *(float4*)&t[kr][nc + (i << 2)] = *(const float4*)(p + (i << 2));
    }
    __syncthreads();
    {
        const int nr = tid >> 2, kc = (tid & 3) << 4;
        union { u16 us[16]; uint4 q[2]; } H;
#pragma unroll
        for (int i = 0; i < 16; i++) H.us[i] = f2h(t[kc + i][nr]);
        const size_t o = (size_t)(n0 + nr) * K + k0 + kc;
        *(uint4*)&dst[o] = H.q[0];
        *(uint4*)&dst[o + 8] = H.q[1];
    }
}

// ---------------------------------------------------------------------------
// LayerNorm (LN2) -> fp16.
// ---------------------------------------------------------------------------
__global__ __launch_bounds__(256) void ln_k(const float* __restrict__ x,
                                            const float* __restrict__ g,
                                            const float* __restrict__ bta,
                                            u16* __restrict__ oh) {
    const int lane = threadIdx.x & 63;
    const int row  = (blockIdx.x << 2) + (threadIdx.x >> 6);
    const float* xr = x + ((size_t)row << 9) + (lane << 3);
    float v[8];
    *(float4*)&v[0] = *(const float4*)xr;
    *(float4*)&v[4] = *(const float4*)(xr + 4);
    float s = 0.f, ss = 0.f;
#pragma unroll
    for (int i = 0; i < 8; i++) { s += v[i]; ss += v[i] * v[i]; }
#pragma unroll
    for (int m = 32; m; m >>= 1) {
        s  += __shfl_xor(s, m, 64);
        ss += __shfl_xor(ss, m, 64);
    }
    const float mu   = s * (1.0f / 512.0f);
    const float rstd = rsqrtf(ss * (1.0f / 512.0f) - mu * mu + 1e-5f);
    float gg[8], bb[8];
    *(float4*)&gg[0] = *(const float4*)(g + (lane << 3));
    *(float4*)&gg[4] = *(const float4*)(g + (lane << 3) + 4);
    *(float4*)&bb[0] = *(const float4*)(bta + (lane << 3));
    *(float4*)&bb[4] = *(const float4*)(bta + (lane << 3) + 4);
    union { u16 us[8]; uint4 q; } H;
#pragma unroll
    for (int i = 0; i < 8; i++) H.us[i] = f2h((v[i] - mu) * rstd * gg[i] + bb[i]);
    *(uint4*)&oh[((size_t)row << 9) + (lane << 3)] = H.q;
}

// ---------------------------------------------------------------------------
// fp16 MFMA GEMM: C = A[M,K]B[K,N]; A fp16 [M][K], B fp16 [N][K].
// 128x128 tile, BK=32, 4 waves 2x2, 16 MFMA : 8 ds_read per k-step,
// double-buffered staging (32KB LDS), asm barriers.
// EPI 0: qkv scatter (q f32 | kh [bh][key][d] | vth via LDS transpose)
// EPI 1/3: +bias +res -> Cf f32     EPI 2: +bias, GELU -> Ch fp16
// ---------------------------------------------------------------------------
template <int EPI>
__global__ __launch_bounds__(256, 3) void sgemm_k(
    const u16* __restrict__ A, const u16* __restrict__ B,
    const float* __restrict__ bias, const float* __restrict__ res,
    float* __restrict__ Cf, u16* __restrict__ Ch, u16* __restrict__ Dh,
    int M, int N, int K) {
    __shared__ u16 sm[16384];  // two 8192-u16 buffers: A[0,4096) B[4096,8192)
    const int tid = threadIdx.x;
    const int lane = tid & 63, wv = tid >> 6;
    const int col = lane & 15, quad = lane >> 4;
    const int wm = (wv & 1) << 6, wn = (wv >> 1) << 6;
    const int bm = blockIdx.y << 7, bn = blockIdx.x << 7;

    const int r0 = tid >> 2,         c0 = (tid & 3) ^ ((r0 >> 1) & 3);
    const int r1 = (tid + 256) >> 2, c1 = (tid & 3) ^ ((r1 >> 1) & 3);
    const u16* Ag0 = A + (size_t)(bm + r0) * K + c0 * 8;
    const u16* Ag1 = A + (size_t)(bm + r1) * K + c1 * 8;
    const u16* Bg0 = B + (size_t)(bn + r0) * K + c0 * 8;
    const u16* Bg1 = B + (size_t)(bn + r1) * K + c1 * 8;
    const int lw0 = wv * 512, lw1 = wv * 512 + 2048;
    const int swz = (col >> 1) & 3;
    const f32x4 z4 = {0.f, 0.f, 0.f, 0.f};
    f32x4 acc[4][4] = {{z4,z4,z4,z4},{z4,z4,z4,z4},{z4,z4,z4,z4},{z4,z4,z4,z4}};

    // prologue: stage k-step 0 into buffer 0
    a16(&sm[lw0],        Ag0);  a16(&sm[lw1],        Ag1);
    a16(&sm[lw0 + 4096], Bg0);  a16(&sm[lw1 + 4096], Bg1);

    int ib = 0;
    for (int k0 = 0; k0 < K; k0 += 32, ib ^= 1) {
        BAR_V0;  // buffer ib ready; all waves past reads of buffer ib^1
        if (k0 + 32 < K) {
            const int nb = (ib ^ 1) * 8192;
            const int kn = k0 + 32;
            a16(&sm[nb + lw0],        Ag0 + kn);  a16(&sm[nb + lw1],        Ag1 + kn);
            a16(&sm[nb + lw0 + 4096], Bg0 + kn);  a16(&sm[nb + lw1 + 4096], Bg1 + kn);
        }
        const int cb = ib * 8192;
        h8 af[4];
#pragma unroll
        for (int mt = 0; mt < 4; mt++) {
            const int ra = cb + (wm + (mt << 4) + col) * 32 + ((quad ^ swz) << 3);
            af[mt] = *(const h8*)&sm[ra];
        }
#pragma unroll
        for (int nt = 0; nt < 4; nt++) {
            const int rb = cb + 4096 + (wn + (nt << 4) + col) * 32 + ((quad ^ swz) << 3);
            h8 bf = *(const h8*)&sm[rb];
#pragma unroll
            for (int mt = 0; mt < 4; mt++)
                acc[mt][nt] = __builtin_amdgcn_mfma_f32_16x16x32_f16(af[mt], bf, acc[mt][nt], 0, 0, 0);
        }
    }

    if constexpr (EPI == 0) {
        if (bn >= 1024) {
            // ---- V region: LDS transpose -> coalesced vth stores ----
            const int hd0  = (bn - 1024) >> 6;
            const int b8   = (bm >> 11) << 3;
            const int keyb = bm & 2047;
            __syncthreads();  // staging buffers done
#pragma unroll
            for (int hf = 0; hf < 2; hf++) {
                if ((wv >> 1) == hf) {
#pragma unroll
                    for (int mt = 0; mt < 4; mt++)
#pragma unroll
                    for (int rr = 0; rr < 4; rr++) {
                        const int key = wm + (mt << 4) + (quad << 2) + rr;
#pragma unroll
                        for (int nt = 0; nt < 4; nt++) {
                            const int dl = (nt << 4) + col;
                            sm[dl * 136 + key] = f2h(acc[mt][nt][rr]);
                        }
                    }
                }
                __syncthreads();
                {
                    const int d = tid >> 2;
#pragma unroll
                    for (int c = 0; c < 4; c++) {
                        const int key0 = ((((tid & 3) << 2) + c) << 3);
                        const size_t gb = ((size_t)(b8 + hd0 + hf) << 17)
                                        + ((size_t)d << 11) + keyb + key0;
                        *(uint4*)&Dh[gb] = *(const uint4*)&sm[d * 136 + key0];
                    }
                }
                __syncthreads();
            }
            return;
        }
    }

    float bs[4];
    if constexpr (EPI >= 1) {
#pragma unroll
        for (int nt = 0; nt < 4; nt++) bs[nt] = bias[bn + wn + (nt << 4) + col];
    }
#pragma unroll
    for (int mt = 0; mt < 4; mt++) {
#pragma unroll
        for (int rr = 0; rr < 4; rr++) {
            const int row = bm + wm + (mt << 4) + (quad << 2) + rr;
#pragma unroll
            for (int nt = 0; nt < 4; nt++) {
                const int colg = bn + wn + (nt << 4) + col;
                float v = acc[mt][nt][rr];
                if constexpr (EPI == 0) {
                    const int b = row >> 11, key = row & 2047;
                    if (bn < 512) {
                        Cf[((size_t)row << 9) + colg] = v;
                    } else {
                        const int hd = (colg - 512) >> 6, d = colg & 63;
                        Ch[((size_t)((b << 3) + hd) << 17) + (key << 6) + d] = f2h(v);
                    }
                } else if constexpr (EPI == 2) {
                    Ch[(size_t)row * N + colg] = f2h(gelu_exact(v + bs[nt]));
                } else {
                    const size_t o = (size_t)row * N + colg;
                    Cf[o] = v + bs[nt] + res[o];
                }
            }
        }
    }
}

// ---------------------------------------------------------------------------
// Flash attention, fp16: 128-thr blocks (2 waves x 2 q-subtiles), grid (32,32).
// K double-buffered; V staged at jt-top, used after softmax; asm barriers
// (vmcnt(4) keeps K prefetch in flight). 16 QK + 16 PV MFMA per wave-jt.
// LDS 32KB (u16 idx): K0[0,4K) K1[4K,8K) V[8K,12K) P[12K,16K)
// ---------------------------------------------------------------------------
__global__ __launch_bounds__(128, 2) void attn_k(const float* __restrict__ q,
                                                 const u16* __restrict__ kh,
                                                 const u16* __restrict__ vth,
                                                 u16* __restrict__ ah) {
    __shared__ u16 sm[16384];
    const int tid = threadIdx.x;
    const int lane = tid & 63, wv = tid >> 6;   // wv in {0,1}
    const int col = lane & 15, quad = lane >> 4;
    const int qt = blockIdx.x, bh = blockIdx.y;
    const int b = bh >> 3, h = bh & 7;
    const size_t tok0 = (size_t)b * SEQ;
    const size_t bhK = (size_t)bh << 17;
    const int q0 = qt << 6;

    // Q fragments, both subtiles (B-operand; 0.125 scale folded in), fp16.
    h8 qf[2][2];
#pragma unroll
    for (int sub = 0; sub < 2; sub++) {
        const int qrow = q0 + (wv << 5) + (sub << 4) + col;
        const float* qp = q + ((tok0 + qrow) << 9) + (h << 6) + (quad << 3);
#pragma unroll
        for (int kc = 0; kc < 2; kc++) {
            float v[8];
            *(float4*)&v[0] = *(const float4*)(qp + (kc << 5));
            *(float4*)&v[4] = *(const float4*)(qp + (kc << 5) + 4);
            union { u16 us[8]; h8 v8; } H;
#pragma unroll
            for (int i = 0; i < 8; i++) H.us[i] = f2h(v[i] * 0.125f);
            qf[sub][kc] = H.v8;
        }
    }

    const f32x4 z4 = {0.f, 0.f, 0.f, 0.f};
    f32x4 o[2][4] = {{z4, z4, z4, z4}, {z4, z4, z4, z4}};
    float m_run[2] = {-1e30f, -1e30f}, l_run[2] = {0.f, 0.f};

    // staging map: 512 chunks/tile; wave wv issue j covers chunk C=(j*2+wv)*64+lane
    size_t kbz[4], vbz[4];
    int doff[4];
#pragma unroll
    for (int j = 0; j < 4; j++) {
        const int C = (((j << 1) + wv) << 6) + lane;
        const int sr = C >> 3, sp = (C & 7) ^ (sr & 7);
        kbz[j] = bhK + ((size_t)sr << 6) + (sp << 3);   // + jt*4096
        vbz[j] = bhK + ((size_t)sr << 11) + (sp << 3);  // + jt*64
        doff[j] = (((j << 1) + wv) << 9);
    }

    // prologue: stage K[0] into K-buffer 0
#pragma unroll
    for (int j = 0; j < 4; j++) a16(&sm[doff[j]], kh + kbz[j]);

    int ib = 0;
    for (int jt = 0; jt < 32; jt++, ib ^= 1) {
        BAR_V0;  // K[jt] retired; all waves done with V[jt-1]/P[jt-1]
        {
            const size_t vo = (size_t)jt << 6;
#pragma unroll
            for (int j = 0; j < 4; j++) a16(&sm[8192 + doff[j]], vth + vbz[j] + vo);
            const size_t kon = (size_t)((jt + 1) & 31) << 12;
            const int nb = (ib ^ 1) << 12;
#pragma unroll
            for (int j = 0; j < 4; j++) a16(&sm[nb + doff[j]], kh + kbz[j] + kon);
        }

        // ---- St[key][q] = K · Qᵀ (K frags feed both subtiles) ----
        const int cb = ib << 12;
        f32x4 st0[4] = {z4, z4, z4, z4}, st1[4] = {z4, z4, z4, z4};
#pragma unroll
        for (int kb = 0; kb < 4; kb++) {
            const int key = (kb << 4) + col;
            const int r64 = key << 6, k7 = key & 7;
#pragma unroll
            for (int kc = 0; kc < 2; kc++) {
                const int ofs = cb + r64 + ((((kc << 2) + quad) ^ k7) << 3);
                h8 kf = *(const h8*)&sm[ofs];
                st0[kb] = __builtin_amdgcn_mfma_f32_16x16x32_f16(kf, qf[0][kc], st0[kb], 0, 0, 0);
                st1[kb] = __builtin_amdgcn_mfma_f32_16x16x32_f16(kf, qf[1][kc], st1[kb], 0, 0, 0);
            }
        }

        // ---- online softmax + P->LDS per subtile ----
#pragma unroll
        for (int sub = 0; sub < 2; sub++) {
            f32x4* st = sub ? st1 : st0;
            float mx = st[0][0];
#pragma unroll
            for (int kb = 0; kb < 4; kb++)
#pragma unroll
                for (int r = 0; r < 4; r++) mx = fmaxf(mx, st[kb][r]);
            mx = fmaxf(mx, __shfl_xor(mx, 16));
            mx = fmaxf(mx, __shfl_xor(mx, 32));
            const float mn = fmaxf(m_run[sub], mx);
            const float alp = __expf(m_run[sub] - mn);
            m_run[sub] = mn;
            float p[16];
            float rs = 0.0f;
#pragma unroll
            for (int kb = 0; kb < 4; kb++)
#pragma unroll
                for (int r = 0; r < 4; r++) {
                    float e = __expf(st[kb][r] - mn);
                    p[(kb << 2) + r] = e;
                    rs += e;
                }
            rs += __shfl_xor(rs, 16);
            rs += __shfl_xor(rs, 32);
            l_run[sub] = l_run[sub] * alp + rs;
            float aO[4];
#pragma unroll
            for (int r = 0; r < 4; r++) aO[r] = __shfl(alp, (quad << 2) + r);
#pragma unroll
            for (int db = 0; db < 4; db++) {
                o[sub][db][0] *= aO[0]; o[sub][db][1] *= aO[1];
                o[sub][db][2] *= aO[2]; o[sub][db][3] *= aO[3];
            }
            const int prow = (wv << 5) + (sub << 4) + col;
            const int p64 = prow << 6, p7 = prow & 7;
#pragma unroll
            for (int kb = 0; kb < 4; kb++) {
                u16x4 hv;
#pragma unroll
                for (int r = 0; r < 4; r++) hv[r] = f2h(p[(kb << 2) + r]);
                const int c = (kb << 1) + (quad >> 1);
                *(u16x4*)&sm[12288 + p64 + ((c ^ p7) << 3) + ((quad & 1) << 2)] = hv;
            }
        }

        BAR_V4;  // 4 V loads retired (oldest); 4 K prefetch stay in flight

        h8 pf[2][2];
#pragma unroll
        for (int sub = 0; sub < 2; sub++) {
            const int prow = (wv << 5) + (sub << 4) + col;
            const int p64 = prow << 6, p7 = prow & 7;
#pragma unroll
            for (int kc = 0; kc < 2; kc++)
                pf[sub][kc] = *(const h8*)&sm[12288 + p64 + ((((kc << 2) + quad) ^ p7) << 3)];
        }
        // ---- O += P · V (V frags feed both subtiles) ----
#pragma unroll
        for (int db = 0; db < 4; db++) {
            const int d = (db << 4) + col;
            const int v64 = 8192 + (d << 6), d7 = d & 7;
#pragma unroll
            for (int kc = 0; kc < 2; kc++) {
                h8 vf = *(const h8*)&sm[v64 + ((((kc << 2) + quad) ^ d7) << 3)];
                o[0][db] = __builtin_amdgcn_mfma_f32_16x16x32_f16(pf[0][kc], vf, o[0][db], 0, 0, 0);
                o[1][db] = __builtin_amdgcn_mfma_f32_16x16x32_f16(pf[1][kc], vf, o[1][db], 0, 0, 0);
            }
        }
    }

    // ---- epilogue: O/l -> fp16 attended [tok][h*64+d] ----
#pragma unroll
    for (int sub = 0; sub < 2; sub++) {
        float linv[4];
#pragma unroll
        for (int r = 0; r < 4; r++) linv[r] = 1.0f / __shfl(l_run[sub], (quad << 2) + r);
#pragma unroll
        for (int r = 0; r < 4; r++) {
            const size_t rowo = ((tok0 + q0 + (wv << 5) + (sub << 4) + (quad << 2) + r) << 9)
                                + (h << 6) + col;
#pragma unroll
            for (int db = 0; db < 4; db++)
                ah[rowo + (db << 4)] = f2h(o[sub][db][r] * linv[r]);
        }
    }
}

// ---------------------------------------------------------------------------
extern "C" void kernel_launch(void* const* d_in, const int* in_sizes, int n_in,
                              void* d_out, int out_size, void* d_ws, size_t ws_size,
                              hipStream_t stream) {
    const float* x     = (const float*)d_in[0];
    const float* ln1_g = (const float*)d_in[1];
    const float* ln1_b = (const float*)d_in[2];
    const float* w_qkv = (const float*)d_in[3];
    const float* w_out = (const float*)d_in[4];
    const float* b_out = (const float*)d_in[5];
    const float* ln2_g = (const float*)d_in[6];
    const float* ln2_b = (const float*)d_in[7];
    const float* w1    = (const float*)d_in[8];
    const float* b1    = (const float*)d_in[9];
    const float* w2    = (const float*)d_in[10];
    const float* b2    = (const float*)d_in[11];
    float* out = (float*)d_out;

    u16* wqkvh = (u16*)d_ws;                       // [1536][512] fp16
    u16* wouth = wqkvh + 1536 * 512;               // [512][512]
    u16* w1h   = wouth + 512 * 512;                // [1024][512]
    u16* w2h   = w1h + 1024 * 512;                 // [512][1024]
    u16* hbuf  = w2h + 512 * 1024;                 // [8192][512] fp16: h/att/mid
    float* qbuf = (float*)(hbuf + (size_t)TOKENS * 512);   // [8192][512] f32
    float* x2   = qbuf;                                    // alias (after attn)
    u16* kh  = (u16*)(qbuf + (size_t)TOKENS * 512);        // [32][2048][64] fp16
    u16* vth = kh + (size_t)32 * 131072;                   // [32][64][2048] fp16
    u16* gh  = kh;                                         // [8192][1024] fp16 (aliases k+v)

    prep_k<<<2560, 256, 0, stream>>>(w_qkv, w_out, w1, w2, wqkvh, wouth, w1h, w2h,
                                     x, ln1_g, ln1_b, hbuf);
    sgemm_k<0><<<dim3(12, 64), 256, 0, stream>>>(hbuf, wqkvh, nullptr, nullptr,
                                                 qbuf, kh, vth, TOKENS, 1536, 512);
    attn_k<<<dim3(32, 32), 128, 0, stream>>>(qbuf, kh, vth, hbuf);
    sgemm_k<1><<<dim3(4, 64), 256, 0, stream>>>(hbuf, wouth, b_out, x,
                                                x2, nullptr, nullptr, TOKENS, 512, 512);
    ln_k<<<TOKENS / 4, 256, 0, stream>>>(x2, ln2_g, ln2_b, hbuf);
    sgemm_k<2><<<dim3(8, 64), 256, 0, stream>>>(hbuf, w1h, b1, nullptr,
                                                nullptr, gh, nullptr, TOKENS, 1024, 512);
    sgemm_k<3><<<dim3(4, 64), 256, 0, stream>>>(gh, w2h, b2, x2,
                                                out, nullptr, nullptr, TOKENS, 512, 1024);
}